// Round 2
// 1096.197 us; speedup vs baseline: 3.8251x; 3.8251x over previous
//
#include <hip/hip_runtime.h>
#include <cmath>

#define B_    2
#define S_    2048
#define H_    4096
#define NH_   32
#define NKV_  8
#define D_    128
#define QKV_N 6144
#define MTOK  4096

typedef __attribute__((ext_vector_type(8))) short bf16x8;
typedef __attribute__((ext_vector_type(4))) float f32x4;
typedef __attribute__((ext_vector_type(4))) unsigned short us4;

#define GLL16(gp, lp)                                                         \
  __builtin_amdgcn_global_load_lds(                                           \
      (const __attribute__((address_space(1))) void*)(gp),                    \
      (__attribute__((address_space(3))) void*)(lp), 16, 0, 0)

__device__ __forceinline__ unsigned short f2bf(float f) {
  unsigned u = __float_as_uint(f);
  u += 0x7fff + ((u >> 16) & 1);   // round-to-nearest-even
  return (unsigned short)(u >> 16);
}

// ---------- float -> bf16 cast (vectorized) ----------
__global__ __launch_bounds__(256) void cast_bf16_kernel(const float* __restrict__ in,
                                                        unsigned short* __restrict__ out,
                                                        int n4) {
  int i = blockIdx.x * blockDim.x + threadIdx.x;
  if (i >= n4) return;
  float4 v = ((const float4*)in)[i];
  us4 o;
  o.x = f2bf(v.x); o.y = f2bf(v.y); o.z = f2bf(v.z); o.w = f2bf(v.w);
  ((us4*)out)[i] = o;
}

// ---------- w (K x N fp32, row-major) -> wt (N x K bf16, row-major) ----------
__global__ __launch_bounds__(256) void transpose_cast_kernel(const float* __restrict__ w,
                                                             unsigned short* __restrict__ wt,
                                                             int K, int N) {
  __shared__ float tile[32][33];
  const int k0 = blockIdx.y * 32, n0 = blockIdx.x * 32;
  const int tid = threadIdx.x;
  const int r = tid >> 3, c4 = (tid & 7) * 4;
  float4 v = *(const float4*)(w + (size_t)(k0 + r) * N + n0 + c4);
  tile[r][c4 + 0] = v.x; tile[r][c4 + 1] = v.y;
  tile[r][c4 + 2] = v.z; tile[r][c4 + 3] = v.w;
  __syncthreads();
  us4 o;
  o.x = f2bf(tile[c4 + 0][r]);
  o.y = f2bf(tile[c4 + 1][r]);
  o.z = f2bf(tile[c4 + 2][r]);
  o.w = f2bf(tile[c4 + 3][r]);
  *(us4*)(wt + (size_t)(n0 + r) * K + k0 + c4) = o;
}

// ---------- bf16 MFMA GEMM (m97 structure): A MxK, Bt NxK, C MxN fp32 ----------
__global__ __launch_bounds__(256) void gemm_bt_kernel(const unsigned short* __restrict__ A,
                                                      const unsigned short* __restrict__ Bt,
                                                      float* __restrict__ C,
                                                      int M, int N, int K) {
  __shared__ short As[128 * 32];
  __shared__ short Bs[128 * 32];
  const int tid = threadIdx.x;
  const int w = tid >> 6, lane = tid & 63;
  const int quad = lane >> 4, l16 = lane & 15;
  const int bm = blockIdx.y, bn = blockIdx.x;
  const int mbase = (w & 1) * 64, nbase = (w >> 1) * 64;

  f32x4 acc[4][4] = {};

  const int srow = w * 32 + (lane >> 2);
  const int skoff = (lane & 3) * 8;
  const unsigned short* Ap = A + (size_t)(bm * 128 + srow) * K + skoff;
  const unsigned short* Bp = Bt + (size_t)(bn * 128 + srow) * K + skoff;

  for (int k0 = 0; k0 < K; k0 += 32) {
    __syncthreads();
#pragma unroll
    for (int i = 0; i < 2; ++i) {
      GLL16(Ap + (size_t)i * 16 * K + k0, As + (w * 32 + i * 16) * 32);
      GLL16(Bp + (size_t)i * 16 * K + k0, Bs + (w * 32 + i * 16) * 32);
    }
    __syncthreads();
    bf16x8 af[4], bfr[4];
#pragma unroll
    for (int mi = 0; mi < 4; ++mi)
      af[mi] = *(const bf16x8*)(As + (mbase + mi * 16 + l16) * 32 + quad * 8);
#pragma unroll
    for (int nj = 0; nj < 4; ++nj)
      bfr[nj] = *(const bf16x8*)(Bs + (nbase + nj * 16 + l16) * 32 + quad * 8);
#pragma unroll
    for (int mi = 0; mi < 4; ++mi)
#pragma unroll
      for (int nj = 0; nj < 4; ++nj)
        acc[mi][nj] = __builtin_amdgcn_mfma_f32_16x16x32_bf16(af[mi], bfr[nj], acc[mi][nj], 0, 0, 0);
  }

  float* Cp = C + (size_t)(bm * 128 + mbase + quad * 4) * N + bn * 128 + nbase + l16;
#pragma unroll
  for (int mi = 0; mi < 4; ++mi)
#pragma unroll
    for (int nj = 0; nj < 4; ++nj)
#pragma unroll
      for (int r = 0; r < 4; ++r)
        Cp[(size_t)(mi * 16 + r) * N + nj * 16] = acc[mi][nj][r];
}

// ---------- fused RoPE (interleaved) + fp32->bf16 cast of full qkv ----------
// grid: x = (QKV_N/2)/256 = 12 blocks of pair-index, y = token
__global__ __launch_bounds__(256) void rope_cast_kernel(const float* __restrict__ qkv,
                                                        const int* __restrict__ positions,
                                                        unsigned short* __restrict__ qkvb) {
  const int tok = blockIdx.y;
  const int p = blockIdx.x * 256 + threadIdx.x;          // pair index 0..3071
  const float2 x = *(const float2*)(qkv + (size_t)tok * QKV_N + 2 * p);
  float o1, o2;
  if (p < (NH_ + NKV_) * (D_ / 2)) {                     // q or k head -> rotate
    const int j = p & 63;
    const float inv = exp2f((float)(2 * j) * (-13.287712379549449f / 128.f));
    const float f = (float)positions[tok] * inv;
    float s, c;
    sincosf(f, &s, &c);
    o1 = x.x * c - x.y * s;
    o2 = x.y * c + x.x * s;
  } else {                                               // v head -> plain cast
    o1 = x.x; o2 = x.y;
  }
  unsigned r = (unsigned)f2bf(o1) | ((unsigned)f2bf(o2) << 16);
  *(unsigned*)(qkvb + (size_t)tok * QKV_N + 2 * p) = r;
}

// ---------- V (bf16, [tok][col]) -> vT [b][kvh][d][S] (bf16) ----------
__global__ __launch_bounds__(256) void vtrans_kernel(const unsigned short* __restrict__ qkvb,
                                                     unsigned short* __restrict__ vT) {
  __shared__ unsigned short t[32][33];
  const int s0 = blockIdx.x * 32;
  const int y0 = blockIdx.y * 32;                        // y = (b*NKV+kvh)*D + d
  const int b = y0 >> 10;
  const int col0 = (NH_ + NKV_) * D_ + (y0 & 1023);      // V slice starts at 5120
  const int tid = threadIdx.x;
  const int r = tid >> 3, c4 = (tid & 7) * 4;
  us4 v = *(const us4*)(qkvb + (size_t)(b * S_ + s0 + r) * QKV_N + col0 + c4);
  t[r][c4 + 0] = v.x; t[r][c4 + 1] = v.y;
  t[r][c4 + 2] = v.z; t[r][c4 + 3] = v.w;
  __syncthreads();
  us4 o;
  o.x = t[c4 + 0][r]; o.y = t[c4 + 1][r];
  o.z = t[c4 + 2][r]; o.w = t[c4 + 3][r];
  *(us4*)(vT + (size_t)(y0 + r) * S_ + s0 + c4) = o;
}

// ---------- bf16 MFMA causal GQA flash attention ----------
// Block: 256 thr = 4 waves, each wave owns 16 q rows (QB=64/block). KV tile = 32.
// Swapped QK^T: S^T = mfma(K_frag, Q_frag) -> lane holds 8 scores of ONE q row
// (q = l16), so softmax reduce is 2 shfl_xor and (m,l) are scalar per lane.
// K in LDS [32][128] bf16 with chunk XOR-swizzle (^row&7), staged by
// global_load_lds from a pre-swizzled global address (rule #21: both sides).
// V pre-transposed in global (vT), staged into LDS [128][32] with 4-chunk
// swizzle so PV B-frags are clean ds_read_b128.
__global__ __launch_bounds__(256) void attn_mfma_kernel(const unsigned short* __restrict__ qkvb,
                                                        const unsigned short* __restrict__ vT,
                                                        unsigned short* __restrict__ aoutb) {
  __shared__ short Ks[32 * 128];
  __shared__ short Vs[128 * 32];
  const int qt = (int)gridDim.x - 1 - (int)blockIdx.x;   // big blocks first
  const int h = blockIdx.y, b = blockIdx.z;
  const int kvh = h >> 2;
  const int tid = threadIdx.x;
  const int w = tid >> 6, lane = tid & 63;
  const int quad = lane >> 4, l16 = lane & 15;

  // ---- Q fragments: lane's q row = l16 (B-operand layout, row-major) ----
  const int qrow = qt * 64 + w * 16 + l16;
  const unsigned short* qp = qkvb + (size_t)(b * S_ + qrow) * QKV_N + h * D_ + quad * 8;
  bf16x8 qf[4];
#pragma unroll
  for (int kk = 0; kk < 4; ++kk) qf[kk] = *(const bf16x8*)(qp + kk * 32);

  // ---- staging source offsets (elements), pre-swizzled ----
  unsigned ks0, ks1, vs0, vs1;
  {
    int i0 = w * 64 + lane;                              // chunk 0..255
    int i1 = i0 + 256;                                   // chunk 256..511
    int r0 = i0 >> 4, c0 = i0 & 15;
    int r1 = i1 >> 4, c1 = i1 & 15;
    int cs0 = (c0 & 8) | ((c0 ^ r0) & 7);
    int cs1 = (c1 & 8) | ((c1 ^ r1) & 7);
    ks0 = (unsigned)(b * S_ + r0) * QKV_N + NH_ * D_ + kvh * D_ + cs0 * 8;
    ks1 = (unsigned)(b * S_ + r1) * QKV_N + NH_ * D_ + kvh * D_ + cs1 * 8;
    int vr0 = i0 >> 2, vc0 = i0 & 3;
    int vr1 = i1 >> 2, vc1 = i1 & 3;
    int vcs0 = vc0 ^ ((vr0 & 3) ^ ((vr0 >> 2) & 3));
    int vcs1 = vc1 ^ ((vr1 & 3) ^ ((vr1 >> 2) & 3));
    vs0 = (unsigned)((b * NKV_ + kvh) * D_ + vr0) * S_ + vcs0 * 8;
    vs1 = (unsigned)((b * NKV_ + kvh) * D_ + vr1) * S_ + vcs1 * 8;
  }
  short* KsW = Ks + w * 512;                             // this wave's 64-chunk region
  short* VsW = Vs + w * 512;

  // ---- per-lane LDS read bases (ushort units) ----
  const int kbase = l16 * 128 + ((quad ^ (l16 & 3)) << 3);       // K A-frag base
  const int mh5 = ((l16 >> 2) & 1) << 5;                          // K swizzle bit2
  const int swl = (l16 & 3) ^ ((l16 >> 2) & 3);                   // V row swizzle
  const int vbase = l16 * 32 + ((quad ^ swl) << 3);               // V B-frag base

  float m = -1e30f, lsum = 0.f;
  f32x4 oacc[8] = {};

  const int qminw = qt * 64 + w * 16;
  const int qmaxw = qminw + 15;
  const int ntiles = 2 * qt + 2;
  const float SCL = 0.08838834764831845f * 1.4426950408889634f;  // rsqrt(128)*log2e

  for (int kt = 0; kt < ntiles; ++kt) {
    const int kb = kt * 32;
    __syncthreads();
    {
      const unsigned short* kgp = qkvb + (size_t)kb * QKV_N;
      GLL16(kgp + ks0, KsW);
      GLL16(kgp + ks1, KsW + 2048);
      GLL16(vT + vs0 + kb, VsW);
      GLL16(vT + vs1 + kb, VsW + 2048);
    }
    __syncthreads();
    if (kb <= qmaxw) {
      // ---- QK^T (swapped): st rows = kv, cols = q ----
      f32x4 st0 = {}, st1 = {};
#pragma unroll
      for (int kk = 0; kk < 4; ++kk) {
        const int ko = (kk << 5) ^ mh5;
        bf16x8 kf0 = *(const bf16x8*)(Ks + kbase + ko);
        bf16x8 kf1 = *(const bf16x8*)(Ks + kbase + 2048 + ko);
        st0 = __builtin_amdgcn_mfma_f32_16x16x32_bf16(kf0, qf[kk], st0, 0, 0, 0);
        st1 = __builtin_amdgcn_mfma_f32_16x16x32_bf16(kf1, qf[kk], st1, 0, 0, 0);
      }
      // lane's 8 scores belong to q=qrow, kv = kb + ct*16 + quad*4 + r
      float sc[8];
#pragma unroll
      for (int r = 0; r < 4; ++r) {
        sc[r] = st0[r] * SCL;
        sc[4 + r] = st1[r] * SCL;
      }
      if (kb + 31 > qminw) {                             // diagonal tile: mask
        const int kvb0 = kb + quad * 4;
#pragma unroll
        for (int r = 0; r < 4; ++r) {
          if (kvb0 + r > qrow) sc[r] = -1e30f;
          if (kvb0 + 16 + r > qrow) sc[4 + r] = -1e30f;
        }
      }
      // ---- online softmax (exp2 domain), state per lane (q = l16) ----
      float cmax = sc[0];
#pragma unroll
      for (int i = 1; i < 8; ++i) cmax = fmaxf(cmax, sc[i]);
      cmax = fmaxf(cmax, __shfl_xor(cmax, 16));
      cmax = fmaxf(cmax, __shfl_xor(cmax, 32));
      const float mn = fmaxf(m, cmax);
      const float alpha = exp2f(m - mn);
      m = mn;
      float p[8];
      float ps = 0.f;
#pragma unroll
      for (int i = 0; i < 8; ++i) { p[i] = exp2f(sc[i] - mn); ps += p[i]; }
      lsum = lsum * alpha + ps;
      // ---- pack P to bf16 pairs, redistribute C-layout -> A-frag via shfl ----
      unsigned pw00 = (unsigned)f2bf(p[0]) | ((unsigned)f2bf(p[1]) << 16);
      unsigned pw01 = (unsigned)f2bf(p[2]) | ((unsigned)f2bf(p[3]) << 16);
      unsigned pw10 = (unsigned)f2bf(p[4]) | ((unsigned)f2bf(p[5]) << 16);
      unsigned pw11 = (unsigned)f2bf(p[6]) | ((unsigned)f2bf(p[7]) << 16);
      const int srcA = l16 + ((quad & 1) << 5);
      const int srcB = srcA + 16;
      unsigned g0 = __shfl(pw00, srcA), g1 = __shfl(pw01, srcA);
      unsigned g2 = __shfl(pw10, srcA), g3 = __shfl(pw11, srcA);
      unsigned h0 = __shfl(pw00, srcB), h1 = __shfl(pw01, srcB);
      unsigned h2 = __shfl(pw10, srcB), h3 = __shfl(pw11, srcB);
      const bool loq = quad < 2;
      union { unsigned u[4]; bf16x8 v; } pu;
      pu.u[0] = loq ? g0 : g2;
      pu.u[1] = loq ? g1 : g3;
      pu.u[2] = loq ? h0 : h2;
      pu.u[3] = loq ? h1 : h3;
      const bf16x8 pf = pu.v;
      // alpha for the O rows this lane accumulates (rows = quad*4 + r)
      const int abase = (lane & 48) | (quad << 2);
      const float al0 = __shfl(alpha, abase);
      const float al1 = __shfl(alpha, abase + 1);
      const float al2 = __shfl(alpha, abase + 2);
      const float al3 = __shfl(alpha, abase + 3);
      // ---- rescale + PV ----
#pragma unroll
      for (int n2 = 0; n2 < 8; ++n2) {
        oacc[n2][0] *= al0; oacc[n2][1] *= al1;
        oacc[n2][2] *= al2; oacc[n2][3] *= al3;
        bf16x8 vf = *(const bf16x8*)(Vs + vbase + n2 * 512);
        oacc[n2] = __builtin_amdgcn_mfma_f32_16x16x32_bf16(pf, vf, oacc[n2], 0, 0, 0);
      }
    }
  }
  // ---- epilogue: finish row sums, normalize, store bf16 ----
  lsum += __shfl_xor(lsum, 16);
  lsum += __shfl_xor(lsum, 32);
  const float inv = 1.f / lsum;
  const int abase = (lane & 48) | (quad << 2);
  const float i0 = __shfl(inv, abase), i1 = __shfl(inv, abase + 1);
  const float i2 = __shfl(inv, abase + 2), i3 = __shfl(inv, abase + 3);
  unsigned short* op = aoutb + (size_t)(b * S_ + qt * 64 + w * 16 + quad * 4) * (NH_ * D_) + h * D_ + l16;
#pragma unroll
  for (int n2 = 0; n2 < 8; ++n2) {
    op[0 * (NH_ * D_) + n2 * 16] = f2bf(oacc[n2][0] * i0);
    op[1 * (NH_ * D_) + n2 * 16] = f2bf(oacc[n2][1] * i1);
    op[2 * (NH_ * D_) + n2 * 16] = f2bf(oacc[n2][2] * i2);
    op[3 * (NH_ * D_) + n2 * 16] = f2bf(oacc[n2][3] * i3);
  }
}

extern "C" void kernel_launch(void* const* d_in, const int* in_sizes, int n_in,
                              void* d_out, int out_size, void* d_ws, size_t ws_size,
                              hipStream_t stream) {
  const float* hs    = (const float*)d_in[0];
  const int*   pos   = (const int*)d_in[1];
  const float* w_qkv = (const float*)d_in[2];
  const float* w_o   = (const float*)d_in[3];
  float* out = (float*)d_out;

  char* wsp = (char*)d_ws;
  float* qkv           = (float*)wsp;                                        // 100.66 MB fp32
  unsigned short* qkvb = (unsigned short*)(wsp + (size_t)MTOK * QKV_N * 4);  // 50.33 MB bf16 (roped)
  unsigned short* bufB = (unsigned short*)(wsp + (size_t)MTOK * QKV_N * 6);  // 33.55 MB (hs_b / w_oT)
  unsigned short* bufC = bufB + (size_t)MTOK * H_;                           // 50.33 MB (w_qkvT / attn_b)
  unsigned short* vT   = bufC + (size_t)MTOK * QKV_N;                        // 8.39 MB

  // 1) cast hs -> bf16 [B]; transpose-cast w_qkv -> [C]
  cast_bf16_kernel<<<(MTOK * H_ / 4 + 255) / 256, 256, 0, stream>>>(hs, bufB, MTOK * H_ / 4);
  {
    dim3 g(QKV_N / 32, H_ / 32);
    transpose_cast_kernel<<<g, 256, 0, stream>>>(w_qkv, bufC, H_, QKV_N);
  }

  // 2) qkv = hs @ w_qkv (bf16 MFMA), fp32 out
  {
    dim3 g(QKV_N / 128, MTOK / 128);
    gemm_bt_kernel<<<g, 256, 0, stream>>>(bufB, bufC, qkv, MTOK, QKV_N, H_);
  }

  // 3) fused RoPE + cast: qkv fp32 -> qkvb bf16
  {
    dim3 g((QKV_N / 2) / 256, MTOK);
    rope_cast_kernel<<<g, 256, 0, stream>>>(qkv, pos, qkvb);
  }

  // 4) V^T for attention PV B-fragments
  {
    dim3 g(S_ / 32, (B_ * NKV_ * D_) / 32);
    vtrans_kernel<<<g, 256, 0, stream>>>(qkvb, vT);
  }

  // 5) bf16 MFMA flash attention -> bufC (bf16, GEMM2 A operand)
  {
    dim3 ga(S_ / 64, NH_, B_);
    attn_mfma_kernel<<<ga, 256, 0, stream>>>(qkvb, vT, bufC);
  }

  // 6) transpose-cast w_o -> [B]
  {
    dim3 g(H_ / 32, H_ / 32);
    transpose_cast_kernel<<<g, 256, 0, stream>>>(w_o, bufB, H_, H_);
  }

  // 7) out = attn @ w_o (bf16 MFMA), fp32 out
  {
    dim3 g(H_ / 128, MTOK / 128);
    gemm_bt_kernel<<<g, 256, 0, stream>>>(bufC, bufB, out, MTOK, H_, NH_ * D_);
  }
}

// Round 4
// 1092.306 us; speedup vs baseline: 3.8387x; 1.0036x over previous
//
#include <hip/hip_runtime.h>
#include <cmath>

#define B_    2
#define S_    2048
#define H_    4096
#define NH_   32
#define NKV_  8
#define D_    128
#define QKV_N 6144
#define MTOK  4096

typedef __attribute__((ext_vector_type(8))) short bf16x8;
typedef __attribute__((ext_vector_type(4))) float f32x4;
typedef __attribute__((ext_vector_type(4))) unsigned short us4;

#define GLL16(gp, lp)                                                         \
  __builtin_amdgcn_global_load_lds(                                           \
      (const __attribute__((address_space(1))) void*)(gp),                    \
      (__attribute__((address_space(3))) void*)(lp), 16, 0, 0)

__device__ __forceinline__ unsigned short f2bf(float f) {
  unsigned u = __float_as_uint(f);
  u += 0x7fff + ((u >> 16) & 1);   // round-to-nearest-even
  return (unsigned short)(u >> 16);
}

// ---------- float -> bf16 cast (vectorized) ----------
__global__ __launch_bounds__(256) void cast_bf16_kernel(const float* __restrict__ in,
                                                        unsigned short* __restrict__ out,
                                                        int n4) {
  int i = blockIdx.x * blockDim.x + threadIdx.x;
  if (i >= n4) return;
  float4 v = ((const float4*)in)[i];
  us4 o;
  o.x = f2bf(v.x); o.y = f2bf(v.y); o.z = f2bf(v.z); o.w = f2bf(v.w);
  ((us4*)out)[i] = o;
}

// ---------- w (K x N fp32, row-major) -> wt (N x K bf16, row-major) ----------
__global__ __launch_bounds__(256) void transpose_cast_kernel(const float* __restrict__ w,
                                                             unsigned short* __restrict__ wt,
                                                             int K, int N) {
  __shared__ float tile[32][33];
  const int k0 = blockIdx.y * 32, n0 = blockIdx.x * 32;
  const int tid = threadIdx.x;
  const int r = tid >> 3, c4 = (tid & 7) * 4;
  float4 v = *(const float4*)(w + (size_t)(k0 + r) * N + n0 + c4);
  tile[r][c4 + 0] = v.x; tile[r][c4 + 1] = v.y;
  tile[r][c4 + 2] = v.z; tile[r][c4 + 3] = v.w;
  __syncthreads();
  us4 o;
  o.x = f2bf(tile[c4 + 0][r]);
  o.y = f2bf(tile[c4 + 1][r]);
  o.z = f2bf(tile[c4 + 2][r]);
  o.w = f2bf(tile[c4 + 3][r]);
  *(us4*)(wt + (size_t)(n0 + r) * K + k0 + c4) = o;
}

// ---------- bf16 MFMA GEMM (m97 structure + XCD swizzle): A MxK, Bt NxK ----------
__global__ __launch_bounds__(256) void gemm_bt_kernel(const unsigned short* __restrict__ A,
                                                      const unsigned short* __restrict__ Bt,
                                                      float* __restrict__ C,
                                                      int M, int N, int K) {
  __shared__ short As[128 * 32];
  __shared__ short Bs[128 * 32];
  const int tid = threadIdx.x;
  const int w = tid >> 6, lane = tid & 63;
  const int quad = lane >> 4, l16 = lane & 15;
  // XCD-aware chunked swizzle (nwg % 8 == 0 for all grids used here)
  const int nx = (int)gridDim.x;
  const int nwg = nx * (int)gridDim.y;
  const int oid = (int)blockIdx.y * nx + (int)blockIdx.x;
  const int cpx = nwg >> 3;
  const int sid = (oid & 7) * cpx + (oid >> 3);
  const int bn = sid % nx, bm = sid / nx;
  const int mbase = (w & 1) * 64, nbase = (w >> 1) * 64;

  f32x4 acc[4][4] = {};

  const int srow = w * 32 + (lane >> 2);
  const int skoff = (lane & 3) * 8;
  const unsigned short* Ap = A + (size_t)(bm * 128 + srow) * K + skoff;
  const unsigned short* Bp = Bt + (size_t)(bn * 128 + srow) * K + skoff;

  for (int k0 = 0; k0 < K; k0 += 32) {
    __syncthreads();
#pragma unroll
    for (int i = 0; i < 2; ++i) {
      GLL16(Ap + (size_t)i * 16 * K + k0, As + (w * 32 + i * 16) * 32);
      GLL16(Bp + (size_t)i * 16 * K + k0, Bs + (w * 32 + i * 16) * 32);
    }
    __syncthreads();
    bf16x8 af[4], bfr[4];
#pragma unroll
    for (int mi = 0; mi < 4; ++mi)
      af[mi] = *(const bf16x8*)(As + (mbase + mi * 16 + l16) * 32 + quad * 8);
#pragma unroll
    for (int nj = 0; nj < 4; ++nj)
      bfr[nj] = *(const bf16x8*)(Bs + (nbase + nj * 16 + l16) * 32 + quad * 8);
#pragma unroll
    for (int mi = 0; mi < 4; ++mi)
#pragma unroll
      for (int nj = 0; nj < 4; ++nj)
        acc[mi][nj] = __builtin_amdgcn_mfma_f32_16x16x32_bf16(af[mi], bfr[nj], acc[mi][nj], 0, 0, 0);
  }

  float* Cp = C + (size_t)(bm * 128 + mbase + quad * 4) * N + bn * 128 + nbase + l16;
#pragma unroll
  for (int mi = 0; mi < 4; ++mi)
#pragma unroll
    for (int nj = 0; nj < 4; ++nj)
#pragma unroll
      for (int r = 0; r < 4; ++r)
        Cp[(size_t)(mi * 16 + r) * N + nj * 16] = acc[mi][nj][r];
}

// ---------- fused RoPE (interleaved) + fp32->bf16 cast of full qkv ----------
__global__ __launch_bounds__(256) void rope_cast_kernel(const float* __restrict__ qkv,
                                                        const int* __restrict__ positions,
                                                        unsigned short* __restrict__ qkvb) {
  const int tok = blockIdx.y;
  const int p = blockIdx.x * 256 + threadIdx.x;          // pair index 0..3071
  const float2 x = *(const float2*)(qkv + (size_t)tok * QKV_N + 2 * p);
  float o1, o2;
  if (p < (NH_ + NKV_) * (D_ / 2)) {                     // q or k head -> rotate
    const int j = p & 63;
    const float inv = exp2f((float)(2 * j) * (-13.287712379549449f / 128.f));
    const float f = (float)positions[tok] * inv;
    float s, c;
    sincosf(f, &s, &c);
    o1 = x.x * c - x.y * s;
    o2 = x.y * c + x.x * s;
  } else {                                               // v head -> plain cast
    o1 = x.x; o2 = x.y;
  }
  unsigned r = (unsigned)f2bf(o1) | ((unsigned)f2bf(o2) << 16);
  *(unsigned*)(qkvb + (size_t)tok * QKV_N + 2 * p) = r;
}

// ---------- V (bf16, [tok][col]) -> vT [b][kvh][d][S] (bf16) ----------
__global__ __launch_bounds__(256) void vtrans_kernel(const unsigned short* __restrict__ qkvb,
                                                     unsigned short* __restrict__ vT) {
  __shared__ unsigned short t[32][33];
  const int s0 = blockIdx.x * 32;
  const int y0 = blockIdx.y * 32;                        // y = (b*NKV+kvh)*D + d
  const int b = y0 >> 10;
  const int col0 = (NH_ + NKV_) * D_ + (y0 & 1023);      // V slice starts at 5120
  const int tid = threadIdx.x;
  const int r = tid >> 3, c4 = (tid & 7) * 4;
  us4 v = *(const us4*)(qkvb + (size_t)(b * S_ + s0 + r) * QKV_N + col0 + c4);
  t[r][c4 + 0] = v.x; t[r][c4 + 1] = v.y;
  t[r][c4 + 2] = v.z; t[r][c4 + 3] = v.w;
  __syncthreads();
  us4 o;
  o.x = t[c4 + 0][r]; o.y = t[c4 + 1][r];
  o.z = t[c4 + 2][r]; o.w = t[c4 + 3][r];
  *(us4*)(vT + (size_t)(y0 + r) * S_ + s0 + c4) = o;
}

// ---------- bf16 MFMA causal GQA flash attention, v2 ----------
// 4 waves/block; each wave owns 32 q rows (2 subtiles of 16) -> 128 q rows/block.
// KV tile = 32, double-buffered LDS, issue-early STAGE + counted vmcnt(4) (T3/T4),
// setprio around MFMA clusters (T5), XCD-aware block swizzle so all blocks of one
// kvh land on one XCD (K+V working set 2MB <= 4MB L2).
__global__ __launch_bounds__(256) void attn_mfma_kernel(const unsigned short* __restrict__ qkvb,
                                                        const unsigned short* __restrict__ vT,
                                                        unsigned short* __restrict__ aoutb) {
  __shared__ short Ks[2][32 * 128];
  __shared__ short Vs[2][32 * 128];
  // inverse XCD swizzle: dispatch p -> logical block o = x + 16*h + 512*b
  const int p = (int)blockIdx.x;
  const int o = ((p >> 3) & 63) + 64 * ((p & 7) + 8 * (p >> 9));
  const int qt = 15 - (o & 15);                          // big q-tiles first per XCD
  const int h = (o >> 4) & 31;
  const int b = o >> 9;
  const int kvh = h >> 2;
  const int tid = threadIdx.x;
  const int w = tid >> 6, lane = tid & 63;
  const int quad = lane >> 4, l16 = lane & 15;
  const int qbase = qt * 128 + w * 32;

  // ---- Q fragments for 2 subtiles: lane's q row = sub*16 + l16 ----
  bf16x8 qf0[4], qf1[4];
  {
    const unsigned short* qp0 = qkvb + (size_t)(b * S_ + qbase + l16) * QKV_N + h * D_ + quad * 8;
    const unsigned short* qp1 = qp0 + (size_t)16 * QKV_N;
#pragma unroll
    for (int kk = 0; kk < 4; ++kk) {
      qf0[kk] = *(const bf16x8*)(qp0 + kk * 32);
      qf1[kk] = *(const bf16x8*)(qp1 + kk * 32);
    }
  }

  // ---- staging source offsets (elements), pre-swizzled ----
  unsigned ks0, ks1, vs0, vs1;
  {
    int i0 = w * 64 + lane;                              // chunk 0..255
    int i1 = i0 + 256;                                   // chunk 256..511
    int r0 = i0 >> 4, c0 = i0 & 15;
    int r1 = i1 >> 4, c1 = i1 & 15;
    int cs0 = (c0 & 8) | ((c0 ^ r0) & 7);
    int cs1 = (c1 & 8) | ((c1 ^ r1) & 7);
    ks0 = (unsigned)(b * S_ + r0) * QKV_N + NH_ * D_ + kvh * D_ + cs0 * 8;
    ks1 = (unsigned)(b * S_ + r1) * QKV_N + NH_ * D_ + kvh * D_ + cs1 * 8;
    int vr0 = i0 >> 2, vc0 = i0 & 3;
    int vr1 = i1 >> 2, vc1 = i1 & 3;
    int vcs0 = vc0 ^ ((vr0 & 3) ^ ((vr0 >> 2) & 3));
    int vcs1 = vc1 ^ ((vr1 & 3) ^ ((vr1 >> 2) & 3));
    vs0 = (unsigned)((b * NKV_ + kvh) * D_ + vr0) * S_ + vcs0 * 8;
    vs1 = (unsigned)((b * NKV_ + kvh) * D_ + vr1) * S_ + vcs1 * 8;
  }

#define STAGE_KV(bufi, kbv)                                                   \
  {                                                                           \
    const unsigned short* kgp_ = qkvb + (size_t)(kbv) * QKV_N;                \
    short* KsW_ = &Ks[bufi][w * 512];                                         \
    short* VsW_ = &Vs[bufi][w * 512];                                         \
    GLL16(kgp_ + ks0, KsW_);                                                  \
    GLL16(kgp_ + ks1, KsW_ + 2048);                                           \
    GLL16(vT + vs0 + (kbv), VsW_);                                            \
    GLL16(vT + vs1 + (kbv), VsW_ + 2048);                                     \
  }

  // ---- per-lane LDS read bases (ushort units) ----
  const int kbase = l16 * 128 + ((quad ^ (l16 & 3)) << 3);       // K A-frag base
  const int mh5 = ((l16 >> 2) & 1) << 5;                          // K swizzle bit2
  const int swl = (l16 & 3) ^ ((l16 >> 2) & 3);                   // V row swizzle
  const int vbase = l16 * 32 + ((quad ^ swl) << 3);               // V B-frag base

  float mreg[2] = {-1e30f, -1e30f};
  float lreg[2] = {0.f, 0.f};
  f32x4 oacc0[8] = {};
  f32x4 oacc1[8] = {};

  const int qmaxw = qbase + 31;
  const int ntiles = 4 * qt + 4;
  const float SCL = 0.08838834764831845f * 1.4426950408889634f;  // rsqrt(128)*log2e

  STAGE_KV(0, 0);
  for (int kt = 0; kt < ntiles; ++kt) {
    const int kb = kt * 32;
    const int cur = kt & 1;
    if (kt + 1 < ntiles) {
      STAGE_KV(cur ^ 1, kb + 32);                        // issue next tile early
      asm volatile("s_waitcnt vmcnt(4)" ::: "memory");   // wait: current done, next in flight
    } else {
      asm volatile("s_waitcnt vmcnt(0)" ::: "memory");
    }
    __builtin_amdgcn_s_barrier();
    if (kb <= qmaxw) {
      const short* Kc = Ks[cur];
      const short* Vc = Vs[cur];
      f32x4 st00 = {}, st01 = {}, st10 = {}, st11 = {};
      __builtin_amdgcn_s_setprio(1);
#pragma unroll
      for (int kk = 0; kk < 4; ++kk) {
        const int ko = (kk << 5) ^ mh5;
        bf16x8 kf0 = *(const bf16x8*)(Kc + kbase + ko);
        bf16x8 kf1 = *(const bf16x8*)(Kc + kbase + 2048 + ko);
        st00 = __builtin_amdgcn_mfma_f32_16x16x32_bf16(kf0, qf0[kk], st00, 0, 0, 0);
        st01 = __builtin_amdgcn_mfma_f32_16x16x32_bf16(kf1, qf0[kk], st01, 0, 0, 0);
        st10 = __builtin_amdgcn_mfma_f32_16x16x32_bf16(kf0, qf1[kk], st10, 0, 0, 0);
        st11 = __builtin_amdgcn_mfma_f32_16x16x32_bf16(kf1, qf1[kk], st11, 0, 0, 0);
      }
      __builtin_amdgcn_s_setprio(0);
      bf16x8 pf[2];
      float al[2][4];
#pragma unroll
      for (int s = 0; s < 2; ++s) {
        const f32x4 a0 = s ? st10 : st00;
        const f32x4 a1 = s ? st11 : st01;
        float sc[8];
#pragma unroll
        for (int r = 0; r < 4; ++r) {
          sc[r] = a0[r] * SCL;
          sc[4 + r] = a1[r] * SCL;
        }
        const int qrow = qbase + s * 16 + l16;
        if (kb + 31 > qbase + s * 16) {                  // diagonal tile: mask
          const int kvb0 = kb + quad * 4;
#pragma unroll
          for (int r = 0; r < 4; ++r) {
            if (kvb0 + r > qrow) sc[r] = -1e30f;
            if (kvb0 + 16 + r > qrow) sc[4 + r] = -1e30f;
          }
        }
        float cmax = sc[0];
#pragma unroll
        for (int i = 1; i < 8; ++i) cmax = fmaxf(cmax, sc[i]);
        cmax = fmaxf(cmax, __shfl_xor(cmax, 16));
        cmax = fmaxf(cmax, __shfl_xor(cmax, 32));
        const float mo = mreg[s];
        const float mn = fmaxf(mo, cmax);
        const float alpha = exp2f(mo - mn);
        mreg[s] = mn;
        float pr[8];
        float ps = 0.f;
#pragma unroll
        for (int i = 0; i < 8; ++i) { pr[i] = exp2f(sc[i] - mn); ps += pr[i]; }
        lreg[s] = lreg[s] * alpha + ps;
        // pack P -> bf16 pairs, redistribute C-layout -> A-frag via shfl
        unsigned pw00 = (unsigned)f2bf(pr[0]) | ((unsigned)f2bf(pr[1]) << 16);
        unsigned pw01 = (unsigned)f2bf(pr[2]) | ((unsigned)f2bf(pr[3]) << 16);
        unsigned pw10 = (unsigned)f2bf(pr[4]) | ((unsigned)f2bf(pr[5]) << 16);
        unsigned pw11 = (unsigned)f2bf(pr[6]) | ((unsigned)f2bf(pr[7]) << 16);
        const int srcA = l16 + ((quad & 1) << 5);
        const int srcB = srcA + 16;
        unsigned g0 = __shfl(pw00, srcA), g1 = __shfl(pw01, srcA);
        unsigned g2 = __shfl(pw10, srcA), g3 = __shfl(pw11, srcA);
        unsigned h0 = __shfl(pw00, srcB), h1 = __shfl(pw01, srcB);
        unsigned h2 = __shfl(pw10, srcB), h3 = __shfl(pw11, srcB);
        const bool loq = quad < 2;
        union { unsigned u[4]; bf16x8 v; } pu;
        pu.u[0] = loq ? g0 : g2;
        pu.u[1] = loq ? g1 : g3;
        pu.u[2] = loq ? h0 : h2;
        pu.u[3] = loq ? h1 : h3;
        pf[s] = pu.v;
        const int abase = (lane & 48) | (quad << 2);
        al[s][0] = __shfl(alpha, abase);
        al[s][1] = __shfl(alpha, abase + 1);
        al[s][2] = __shfl(alpha, abase + 2);
        al[s][3] = __shfl(alpha, abase + 3);
      }
      // ---- rescale + PV (V frag shared by both subtiles) ----
      __builtin_amdgcn_s_setprio(1);
#pragma unroll
      for (int n2 = 0; n2 < 8; ++n2) {
        bf16x8 vf = *(const bf16x8*)(Vc + vbase + n2 * 512);
        oacc0[n2][0] *= al[0][0]; oacc0[n2][1] *= al[0][1];
        oacc0[n2][2] *= al[0][2]; oacc0[n2][3] *= al[0][3];
        oacc0[n2] = __builtin_amdgcn_mfma_f32_16x16x32_bf16(pf[0], vf, oacc0[n2], 0, 0, 0);
        oacc1[n2][0] *= al[1][0]; oacc1[n2][1] *= al[1][1];
        oacc1[n2][2] *= al[1][2]; oacc1[n2][3] *= al[1][3];
        oacc1[n2] = __builtin_amdgcn_mfma_f32_16x16x32_bf16(pf[1], vf, oacc1[n2], 0, 0, 0);
      }
      __builtin_amdgcn_s_setprio(0);
    }
    __builtin_amdgcn_s_barrier();
  }

  // ---- epilogue: finish row sums, normalize, store bf16 ----
#define ATTN_EPI(sI, OA)                                                      \
  {                                                                           \
    float lsv = lreg[sI];                                                     \
    lsv += __shfl_xor(lsv, 16);                                               \
    lsv += __shfl_xor(lsv, 32);                                               \
    const float inv = 1.f / lsv;                                              \
    const int ab_ = (lane & 48) | (quad << 2);                                \
    const float i0 = __shfl(inv, ab_), i1 = __shfl(inv, ab_ + 1);             \
    const float i2 = __shfl(inv, ab_ + 2), i3 = __shfl(inv, ab_ + 3);         \
    unsigned short* op = aoutb +                                              \
        (size_t)(b * S_ + qbase + sI * 16 + quad * 4) * (NH_ * D_) +          \
        h * D_ + l16;                                                         \
    _Pragma("unroll")                                                         \
    for (int n2 = 0; n2 < 8; ++n2) {                                          \
      op[0 * (NH_ * D_) + n2 * 16] = f2bf(OA[n2][0] * i0);                    \
      op[1 * (NH_ * D_) + n2 * 16] = f2bf(OA[n2][1] * i1);                    \
      op[2 * (NH_ * D_) + n2 * 16] = f2bf(OA[n2][2] * i2);                    \
      op[3 * (NH_ * D_) + n2 * 16] = f2bf(OA[n2][3] * i3);                    \
    }                                                                         \
  }
  ATTN_EPI(0, oacc0);
  ATTN_EPI(1, oacc1);
#undef ATTN_EPI
#undef STAGE_KV
}

extern "C" void kernel_launch(void* const* d_in, const int* in_sizes, int n_in,
                              void* d_out, int out_size, void* d_ws, size_t ws_size,
                              hipStream_t stream) {
  const float* hs    = (const float*)d_in[0];
  const int*   pos   = (const int*)d_in[1];
  const float* w_qkv = (const float*)d_in[2];
  const float* w_o   = (const float*)d_in[3];
  float* out = (float*)d_out;

  char* wsp = (char*)d_ws;
  float* qkv           = (float*)wsp;                                        // fp32 qkv
  unsigned short* qkvb = (unsigned short*)(wsp + (size_t)MTOK * QKV_N * 4);  // bf16 roped qkv
  unsigned short* bufB = (unsigned short*)(wsp + (size_t)MTOK * QKV_N * 6);  // hs_b / w_oT
  unsigned short* bufC = bufB + (size_t)MTOK * H_;                           // w_qkvT / attn_b
  unsigned short* vT   = bufC + (size_t)MTOK * QKV_N;                        // V^T

  // 1) cast hs -> bf16 [B]; transpose-cast w_qkv -> [C]
  cast_bf16_kernel<<<(MTOK * H_ / 4 + 255) / 256, 256, 0, stream>>>(hs, bufB, MTOK * H_ / 4);
  {
    dim3 g(QKV_N / 32, H_ / 32);
    transpose_cast_kernel<<<g, 256, 0, stream>>>(w_qkv, bufC, H_, QKV_N);
  }

  // 2) qkv = hs @ w_qkv (bf16 MFMA), fp32 out
  {
    dim3 g(QKV_N / 128, MTOK / 128);
    gemm_bt_kernel<<<g, 256, 0, stream>>>(bufB, bufC, qkv, MTOK, QKV_N, H_);
  }

  // 3) fused RoPE + cast: qkv fp32 -> qkvb bf16
  {
    dim3 g((QKV_N / 2) / 256, MTOK);
    rope_cast_kernel<<<g, 256, 0, stream>>>(qkv, pos, qkvb);
  }

  // 4) V^T for attention PV B-fragments
  {
    dim3 g(S_ / 32, (B_ * NKV_ * D_) / 32);
    vtrans_kernel<<<g, 256, 0, stream>>>(qkvb, vT);
  }

  // 5) bf16 MFMA flash attention -> bufC (bf16, GEMM2 A operand)
  {
    dim3 ga((S_ / 128) * NH_ * B_);                      // 1024 blocks, XCD-swizzled
    attn_mfma_kernel<<<ga, 256, 0, stream>>>(qkvb, vT, bufC);
  }

  // 6) transpose-cast w_o -> [B]
  {
    dim3 g(H_ / 32, H_ / 32);
    transpose_cast_kernel<<<g, 256, 0, stream>>>(w_o, bufB, H_, H_);
  }

  // 7) out = attn @ w_o (bf16 MFMA), fp32 out
  {
    dim3 g(H_ / 128, MTOK / 128);
    gemm_bt_kernel<<<g, 256, 0, stream>>>(bufC, bufB, out, MTOK, H_, NH_ * D_);
  }
}

// Round 5
// 999.114 us; speedup vs baseline: 4.1968x; 1.0933x over previous
//
#include <hip/hip_runtime.h>
#include <cmath>

#define B_    2
#define S_    2048
#define H_    4096
#define NH_   32
#define NKV_  8
#define D_    128
#define QKV_N 6144
#define MTOK  4096

typedef __attribute__((ext_vector_type(8))) short bf16x8;
typedef __attribute__((ext_vector_type(4))) float f32x4;
typedef __attribute__((ext_vector_type(4))) unsigned short us4;

#define GLL16(gp, lp)                                                         \
  __builtin_amdgcn_global_load_lds(                                           \
      (const __attribute__((address_space(1))) void*)(gp),                    \
      (__attribute__((address_space(3))) void*)(lp), 16, 0, 0)

__device__ __forceinline__ unsigned short f2bf(float f) {
  unsigned u = __float_as_uint(f);
  u += 0x7fff + ((u >> 16) & 1);   // round-to-nearest-even
  return (unsigned short)(u >> 16);
}

// ---------- float -> bf16 cast (vectorized) ----------
__global__ __launch_bounds__(256) void cast_bf16_kernel(const float* __restrict__ in,
                                                        unsigned short* __restrict__ out,
                                                        int n4) {
  int i = blockIdx.x * blockDim.x + threadIdx.x;
  if (i >= n4) return;
  float4 v = ((const float4*)in)[i];
  us4 o;
  o.x = f2bf(v.x); o.y = f2bf(v.y); o.z = f2bf(v.z); o.w = f2bf(v.w);
  ((us4*)out)[i] = o;
}

// ---------- w (K x N fp32, row-major) -> wt (N x K bf16, row-major) ----------
__global__ __launch_bounds__(256) void transpose_cast_kernel(const float* __restrict__ w,
                                                             unsigned short* __restrict__ wt,
                                                             int K, int N) {
  __shared__ float tile[32][33];
  const int k0 = blockIdx.y * 32, n0 = blockIdx.x * 32;
  const int tid = threadIdx.x;
  const int r = tid >> 3, c4 = (tid & 7) * 4;
  float4 v = *(const float4*)(w + (size_t)(k0 + r) * N + n0 + c4);
  tile[r][c4 + 0] = v.x; tile[r][c4 + 1] = v.y;
  tile[r][c4 + 2] = v.z; tile[r][c4 + 3] = v.w;
  __syncthreads();
  us4 o;
  o.x = f2bf(tile[c4 + 0][r]);
  o.y = f2bf(tile[c4 + 1][r]);
  o.z = f2bf(tile[c4 + 2][r]);
  o.w = f2bf(tile[c4 + 3][r]);
  *(us4*)(wt + (size_t)(n0 + r) * K + k0 + c4) = o;
}

// ---------- bf16 MFMA GEMM (m97 structure + XCD swizzle): A MxK, Bt NxK ----------
__global__ __launch_bounds__(256) void gemm_bt_kernel(const unsigned short* __restrict__ A,
                                                      const unsigned short* __restrict__ Bt,
                                                      float* __restrict__ C,
                                                      int M, int N, int K) {
  __shared__ short As[128 * 32];
  __shared__ short Bs[128 * 32];
  const int tid = threadIdx.x;
  const int w = tid >> 6, lane = tid & 63;
  const int quad = lane >> 4, l16 = lane & 15;
  // XCD-aware chunked swizzle (nwg % 8 == 0 for all grids used here)
  const int nx = (int)gridDim.x;
  const int nwg = nx * (int)gridDim.y;
  const int oid = (int)blockIdx.y * nx + (int)blockIdx.x;
  const int cpx = nwg >> 3;
  const int sid = (oid & 7) * cpx + (oid >> 3);
  const int bn = sid % nx, bm = sid / nx;
  const int mbase = (w & 1) * 64, nbase = (w >> 1) * 64;

  f32x4 acc[4][4] = {};

  const int srow = w * 32 + (lane >> 2);
  const int skoff = (lane & 3) * 8;
  const unsigned short* Ap = A + (size_t)(bm * 128 + srow) * K + skoff;
  const unsigned short* Bp = Bt + (size_t)(bn * 128 + srow) * K + skoff;

  for (int k0 = 0; k0 < K; k0 += 32) {
    __syncthreads();
#pragma unroll
    for (int i = 0; i < 2; ++i) {
      GLL16(Ap + (size_t)i * 16 * K + k0, As + (w * 32 + i * 16) * 32);
      GLL16(Bp + (size_t)i * 16 * K + k0, Bs + (w * 32 + i * 16) * 32);
    }
    __syncthreads();
    bf16x8 af[4], bfr[4];
#pragma unroll
    for (int mi = 0; mi < 4; ++mi)
      af[mi] = *(const bf16x8*)(As + (mbase + mi * 16 + l16) * 32 + quad * 8);
#pragma unroll
    for (int nj = 0; nj < 4; ++nj)
      bfr[nj] = *(const bf16x8*)(Bs + (nbase + nj * 16 + l16) * 32 + quad * 8);
#pragma unroll
    for (int mi = 0; mi < 4; ++mi)
#pragma unroll
      for (int nj = 0; nj < 4; ++nj)
        acc[mi][nj] = __builtin_amdgcn_mfma_f32_16x16x32_bf16(af[mi], bfr[nj], acc[mi][nj], 0, 0, 0);
  }

  float* Cp = C + (size_t)(bm * 128 + mbase + quad * 4) * N + bn * 128 + nbase + l16;
#pragma unroll
  for (int mi = 0; mi < 4; ++mi)
#pragma unroll
    for (int nj = 0; nj < 4; ++nj)
#pragma unroll
      for (int r = 0; r < 4; ++r)
        Cp[(size_t)(mi * 16 + r) * N + nj * 16] = acc[mi][nj][r];
}

// ---------- fused RoPE (interleaved) + fp32->bf16 cast of full qkv ----------
__global__ __launch_bounds__(256) void rope_cast_kernel(const float* __restrict__ qkv,
                                                        const int* __restrict__ positions,
                                                        unsigned short* __restrict__ qkvb) {
  const int tok = blockIdx.y;
  const int p = blockIdx.x * 256 + threadIdx.x;          // pair index 0..3071
  const float2 x = *(const float2*)(qkv + (size_t)tok * QKV_N + 2 * p);
  float o1, o2;
  if (p < (NH_ + NKV_) * (D_ / 2)) {                     // q or k head -> rotate
    const int j = p & 63;
    const float inv = exp2f((float)(2 * j) * (-13.287712379549449f / 128.f));
    const float f = (float)positions[tok] * inv;
    float s, c;
    sincosf(f, &s, &c);
    o1 = x.x * c - x.y * s;
    o2 = x.y * c + x.x * s;
  } else {                                               // v head -> plain cast
    o1 = x.x; o2 = x.y;
  }
  unsigned r = (unsigned)f2bf(o1) | ((unsigned)f2bf(o2) << 16);
  *(unsigned*)(qkvb + (size_t)tok * QKV_N + 2 * p) = r;
}

// ---------- V (bf16, [tok][col]) -> vT [b][kvh][d][S] (bf16) ----------
__global__ __launch_bounds__(256) void vtrans_kernel(const unsigned short* __restrict__ qkvb,
                                                     unsigned short* __restrict__ vT) {
  __shared__ unsigned short t[32][33];
  const int s0 = blockIdx.x * 32;
  const int y0 = blockIdx.y * 32;                        // y = (b*NKV+kvh)*D + d
  const int b = y0 >> 10;
  const int col0 = (NH_ + NKV_) * D_ + (y0 & 1023);      // V slice starts at 5120
  const int tid = threadIdx.x;
  const int r = tid >> 3, c4 = (tid & 7) * 4;
  us4 v = *(const us4*)(qkvb + (size_t)(b * S_ + s0 + r) * QKV_N + col0 + c4);
  t[r][c4 + 0] = v.x; t[r][c4 + 1] = v.y;
  t[r][c4 + 2] = v.z; t[r][c4 + 3] = v.w;
  __syncthreads();
  us4 o;
  o.x = t[c4 + 0][r]; o.y = t[c4 + 1][r];
  o.z = t[c4 + 2][r]; o.w = t[c4 + 3][r];
  *(us4*)(vT + (size_t)(y0 + r) * S_ + s0 + c4) = o;
}

// ---------- bf16 MFMA causal GQA flash attention, v3 ----------
// 1 wave per block, 32 q rows/wave (2 subtiles of 16), KV tile = 32.
// NO LDS, NO barriers: K/V fragments loaded global->VGPR (K/V is L2-resident,
// proven by r4 FETCH counters; staging L2-fit data is pure overhead, m169).
// 4096 independent blocks -> fine load balance + many independent waves/SIMD
// to hide the softmax latency chains. Defer-max (T13, THR=8 exp2-domain) skips
// the cross-lane max reduce + alpha broadcast + O-rescale in the common case.
// XCD swizzle keeps each kvh's K/V (2MB) pinned to one XCD's L2.
__global__ __launch_bounds__(64) void attn_mfma_kernel(const unsigned short* __restrict__ qkvb,
                                                       const unsigned short* __restrict__ vT,
                                                       unsigned short* __restrict__ aoutb) {
  // block decode: xcd = p&7 (dispatch round-robin), within-XCD big-q-tiles first
  const int p = (int)blockIdx.x;
  const int xcd = p & 7;
  const int o = p >> 3;                  // 0..511 per XCD
  const int qt = 63 - (o >> 3);          // 64 q-tiles, heavy first
  const int hl = (o >> 1) & 3;
  const int b = o & 1;
  const int h = xcd * 4 + hl;            // kvh = h>>2 = xcd -> L2 pinning
  const int kvh = xcd;
  const int lane = (int)threadIdx.x & 63;
  const int quad = lane >> 4, l16 = lane & 15;
  const int qbase = qt * 32;

  // ---- Q fragments for 2 subtiles: lane's q row = sub*16 + l16 ----
  bf16x8 qf0[4], qf1[4];
  {
    const unsigned short* qp0 = qkvb + (size_t)(b * S_ + qbase + l16) * QKV_N + h * D_ + quad * 8;
    const unsigned short* qp1 = qp0 + (size_t)16 * QKV_N;
#pragma unroll
    for (int kk = 0; kk < 4; ++kk) {
      qf0[kk] = *(const bf16x8*)(qp0 + kk * 32);
      qf1[kk] = *(const bf16x8*)(qp1 + kk * 32);
    }
  }

  // per-lane K/V global bases
  const unsigned short* kp = qkvb + (size_t)(b * S_ + l16) * QKV_N + NH_ * D_ + kvh * D_ + quad * 8;
  const unsigned short* vp = vT + (size_t)((b * NKV_ + kvh) * D_ + l16) * S_ + quad * 8;

  float mreg[2] = {-1e30f, -1e30f};
  float lreg[2] = {0.f, 0.f};
  f32x4 oacc0[8] = {};
  f32x4 oacc1[8] = {};

  const float SCL = 0.08838834764831845f * 1.4426950408889634f;  // rsqrt(128)*log2e

  for (int kt = 0; kt <= qt; ++kt) {
    const int kb = kt * 32;
    // ---- K fragments (rows l16 / l16+16 of the 32-kv tile) ----
    const unsigned short* kpt = kp + (size_t)kb * QKV_N;
    bf16x8 kf0[4], kf1[4];
#pragma unroll
    for (int kk = 0; kk < 4; ++kk) {
      kf0[kk] = *(const bf16x8*)(kpt + kk * 32);
      kf1[kk] = *(const bf16x8*)(kpt + (size_t)16 * QKV_N + kk * 32);
    }
    // ---- V fragments (issued early; consumed after softmax) ----
    bf16x8 vf[8];
#pragma unroll
    for (int n2 = 0; n2 < 8; ++n2)
      vf[n2] = *(const bf16x8*)(vp + (size_t)(n2 * 16) * S_ + kb);

    // ---- QK^T (swapped): rows = kv, cols = q ----
    f32x4 st00 = {}, st01 = {}, st10 = {}, st11 = {};
    __builtin_amdgcn_s_setprio(1);
#pragma unroll
    for (int kk = 0; kk < 4; ++kk) {
      st00 = __builtin_amdgcn_mfma_f32_16x16x32_bf16(kf0[kk], qf0[kk], st00, 0, 0, 0);
      st01 = __builtin_amdgcn_mfma_f32_16x16x32_bf16(kf1[kk], qf0[kk], st01, 0, 0, 0);
      st10 = __builtin_amdgcn_mfma_f32_16x16x32_bf16(kf0[kk], qf1[kk], st10, 0, 0, 0);
      st11 = __builtin_amdgcn_mfma_f32_16x16x32_bf16(kf1[kk], qf1[kk], st11, 0, 0, 0);
    }
    __builtin_amdgcn_s_setprio(0);

    bf16x8 pf[2];
#pragma unroll
    for (int s = 0; s < 2; ++s) {
      const f32x4 a0 = s ? st10 : st00;
      const f32x4 a1 = s ? st11 : st01;
      float sc[8];
#pragma unroll
      for (int r = 0; r < 4; ++r) {
        sc[r] = a0[r] * SCL;
        sc[4 + r] = a1[r] * SCL;
      }
      const int qrow = qbase + s * 16 + l16;
      if (kt == qt) {                                    // diagonal tile: mask
        const int kvb0 = kb + quad * 4;
#pragma unroll
        for (int r = 0; r < 4; ++r) {
          if (kvb0 + r > qrow) sc[r] = -1e30f;
          if (kvb0 + 16 + r > qrow) sc[4 + r] = -1e30f;
        }
      }
      float pmax = sc[0];
#pragma unroll
      for (int i = 1; i < 8; ++i) pmax = fmaxf(pmax, sc[i]);
      const float mo = mreg[s];
      // defer-max: only rescale when the running max grew by > 8 (exp2-domain)
      if (!__all(pmax - mo <= 8.f)) {
        float cmax = fmaxf(pmax, __shfl_xor(pmax, 16));
        cmax = fmaxf(cmax, __shfl_xor(cmax, 32));
        const float mn = fmaxf(mo, cmax);
        const float alpha = exp2f(mo - mn);
        mreg[s] = mn;
        lreg[s] *= alpha;
        const int abase = (lane & 48) | (quad << 2);
        const float al0 = __shfl(alpha, abase);
        const float al1 = __shfl(alpha, abase + 1);
        const float al2 = __shfl(alpha, abase + 2);
        const float al3 = __shfl(alpha, abase + 3);
        f32x4* OA = s ? oacc1 : oacc0;
#pragma unroll
        for (int n2 = 0; n2 < 8; ++n2) {
          OA[n2][0] *= al0; OA[n2][1] *= al1;
          OA[n2][2] *= al2; OA[n2][3] *= al3;
        }
      }
      const float mn2 = mreg[s];
      float pr[8];
      float ps = 0.f;
#pragma unroll
      for (int i = 0; i < 8; ++i) { pr[i] = exp2f(sc[i] - mn2); ps += pr[i]; }
      lreg[s] += ps;
      // pack P -> bf16 pairs, redistribute C-layout -> A-frag via shfl
      unsigned pw00 = (unsigned)f2bf(pr[0]) | ((unsigned)f2bf(pr[1]) << 16);
      unsigned pw01 = (unsigned)f2bf(pr[2]) | ((unsigned)f2bf(pr[3]) << 16);
      unsigned pw10 = (unsigned)f2bf(pr[4]) | ((unsigned)f2bf(pr[5]) << 16);
      unsigned pw11 = (unsigned)f2bf(pr[6]) | ((unsigned)f2bf(pr[7]) << 16);
      const int srcA = l16 + ((quad & 1) << 5);
      const int srcB = srcA + 16;
      unsigned g0 = __shfl(pw00, srcA), g1 = __shfl(pw01, srcA);
      unsigned g2 = __shfl(pw10, srcA), g3 = __shfl(pw11, srcA);
      unsigned h0 = __shfl(pw00, srcB), h1 = __shfl(pw01, srcB);
      unsigned h2 = __shfl(pw10, srcB), h3 = __shfl(pw11, srcB);
      const bool loq = quad < 2;
      union { unsigned u[4]; bf16x8 v; } pu;
      pu.u[0] = loq ? g0 : g2;
      pu.u[1] = loq ? g1 : g3;
      pu.u[2] = loq ? h0 : h2;
      pu.u[3] = loq ? h1 : h3;
      pf[s] = pu.v;
    }

    // ---- PV (V frags shared by both subtiles) ----
    __builtin_amdgcn_s_setprio(1);
#pragma unroll
    for (int n2 = 0; n2 < 8; ++n2) {
      oacc0[n2] = __builtin_amdgcn_mfma_f32_16x16x32_bf16(pf[0], vf[n2], oacc0[n2], 0, 0, 0);
      oacc1[n2] = __builtin_amdgcn_mfma_f32_16x16x32_bf16(pf[1], vf[n2], oacc1[n2], 0, 0, 0);
    }
    __builtin_amdgcn_s_setprio(0);
  }

  // ---- epilogue: finish row sums, normalize, store bf16 ----
#define ATTN_EPI(sI, OA)                                                      \
  {                                                                           \
    float lsv = lreg[sI];                                                     \
    lsv += __shfl_xor(lsv, 16);                                               \
    lsv += __shfl_xor(lsv, 32);                                               \
    const float inv = 1.f / lsv;                                              \
    const int ab_ = (lane & 48) | (quad << 2);                                \
    const float i0 = __shfl(inv, ab_), i1 = __shfl(inv, ab_ + 1);             \
    const float i2 = __shfl(inv, ab_ + 2), i3 = __shfl(inv, ab_ + 3);         \
    unsigned short* op = aoutb +                                              \
        (size_t)(b * S_ + qbase + sI * 16 + quad * 4) * (NH_ * D_) +          \
        h * D_ + l16;                                                         \
    _Pragma("unroll")                                                         \
    for (int n2 = 0; n2 < 8; ++n2) {                                          \
      op[0 * (NH_ * D_) + n2 * 16] = f2bf(OA[n2][0] * i0);                    \
      op[1 * (NH_ * D_) + n2 * 16] = f2bf(OA[n2][1] * i1);                    \
      op[2 * (NH_ * D_) + n2 * 16] = f2bf(OA[n2][2] * i2);                    \
      op[3 * (NH_ * D_) + n2 * 16] = f2bf(OA[n2][3] * i3);                    \
    }                                                                         \
  }
  ATTN_EPI(0, oacc0);
  ATTN_EPI(1, oacc1);
#undef ATTN_EPI
}

extern "C" void kernel_launch(void* const* d_in, const int* in_sizes, int n_in,
                              void* d_out, int out_size, void* d_ws, size_t ws_size,
                              hipStream_t stream) {
  const float* hs    = (const float*)d_in[0];
  const int*   pos   = (const int*)d_in[1];
  const float* w_qkv = (const float*)d_in[2];
  const float* w_o   = (const float*)d_in[3];
  float* out = (float*)d_out;

  char* wsp = (char*)d_ws;
  float* qkv           = (float*)wsp;                                        // fp32 qkv
  unsigned short* qkvb = (unsigned short*)(wsp + (size_t)MTOK * QKV_N * 4);  // bf16 roped qkv
  unsigned short* bufB = (unsigned short*)(wsp + (size_t)MTOK * QKV_N * 6);  // hs_b / w_oT
  unsigned short* bufC = bufB + (size_t)MTOK * H_;                           // w_qkvT / attn_b
  unsigned short* vT   = bufC + (size_t)MTOK * QKV_N;                        // V^T

  // 1) cast hs -> bf16 [B]; transpose-cast w_qkv -> [C]
  cast_bf16_kernel<<<(MTOK * H_ / 4 + 255) / 256, 256, 0, stream>>>(hs, bufB, MTOK * H_ / 4);
  {
    dim3 g(QKV_N / 32, H_ / 32);
    transpose_cast_kernel<<<g, 256, 0, stream>>>(w_qkv, bufC, H_, QKV_N);
  }

  // 2) qkv = hs @ w_qkv (bf16 MFMA), fp32 out
  {
    dim3 g(QKV_N / 128, MTOK / 128);
    gemm_bt_kernel<<<g, 256, 0, stream>>>(bufB, bufC, qkv, MTOK, QKV_N, H_);
  }

  // 3) fused RoPE + cast: qkv fp32 -> qkvb bf16
  {
    dim3 g((QKV_N / 2) / 256, MTOK);
    rope_cast_kernel<<<g, 256, 0, stream>>>(qkv, pos, qkvb);
  }

  // 4) V^T for attention PV B-fragments
  {
    dim3 g(S_ / 32, (B_ * NKV_ * D_) / 32);
    vtrans_kernel<<<g, 256, 0, stream>>>(qkvb, vT);
  }

  // 5) bf16 MFMA flash attention -> bufC (bf16, GEMM2 A operand)
  attn_mfma_kernel<<<(S_ / 32) * NH_ * B_, 64, 0, stream>>>(qkvb, vT, bufC);

  // 6) transpose-cast w_o -> [B]
  {
    dim3 g(H_ / 32, H_ / 32);
    transpose_cast_kernel<<<g, 256, 0, stream>>>(w_o, bufB, H_, H_);
  }

  // 7) out = attn @ w_o (bf16 MFMA), fp32 out
  {
    dim3 g(H_ / 128, MTOK / 128);
    gemm_bt_kernel<<<g, 256, 0, stream>>>(bufC, bufB, out, MTOK, H_, NH_ * D_);
  }
}